// Round 4
// baseline (480.557 us; speedup 1.0000x reference)
//
#include <hip/hip_runtime.h>

// LocallyConnected2D: y[n,h,w] = relu(sum_{i,j} x[n,h+i,w+j]*W[h,w,i,j] + b[h,w])
// lane = batch n (N=64=wave). History:
//  R1: scalar (SMEM) weights -> lgkmcnt drains mixed with ds_read. Clean regs.
//  R2: f[12] local array -> scratch (223MB writes).
//  R3: VMEM uniform weights + full unroll -> hoist pressure -> spill (191MB).
//  R4: weights via LDS broadcast (full unroll) -> hoisted ds_reads, spill.
//  R5: manual cur/nxt prefetch + memory clobber -> arrays in scratch (1.78GB).
//  R6: sched_barrier(0x7) regions -> allocator catastrophe (3.68GB scratch).
//  R7: runtime r loop, weights as per-iter uniform VMEM loads. 284us.
//  R8: weights bulk-staged to LDS, 18 broadcast ds_read_b128/iter. 205us.
//      LDS-pipe-bound (162 bcast b128/wave on shared per-CU pipe).
//  R9: weights global->VGPR pack, hot loop = readlane+fma, x-tile XOR-swizzle.
//      172us. VALUBusy 55, HBM 24%, occ 30. Budget: per 3-block CU round,
//      HBM share 17.4k cyc >> VALU 8k >> LDS 5k, realized only ~43% ->
//      staging-serialization bound (short-lived blocks, cold 48KB burst
//      serial with compute; x requested 6x unique from tiny tiles).
//  R10: persistent blocks (768 = 3/CU), contiguous ty-runs (~10 tiles share
//      8/12 x rows -> L1/L2 hits), per-tile software pipeline (issue next
//      tile's loads at top of compute), nt hints on weights/out.
//      FAILED TO COMPILE: __builtin_nontemporal_store needs ext_vector_type,
//      not HIP_vector_type float4.
//  R11 (this): R10 with nt stores through ext_vector float4 (f4v). No other
//      change.

#define H_IN 512
#define W_IN 512
#define H_OUT 504
#define W_OUT 504
#define W_T 8
#define H_T 4
#define TROWS (H_T + 8)       // 12 staged input rows
#define XF (TROWS * 1024)     // 12288 floats = 48 KB -> 3 blocks/CU
#define NTX 63                // tiles in w
#define NTY 126               // tiles in h
#define NT (NTX * NTY)        // 7938
#define NBLK 768              // 256 CUs x 3 resident blocks

typedef float f4v __attribute__((ext_vector_type(4)));   // for nt store/load

__device__ __forceinline__ float readlane_f(float v, int l) {
    return __int_as_float(__builtin_amdgcn_readlane(__float_as_int(v), l));
}

__launch_bounds__(256, 3)
__global__ void lc2d_kernel(const float* __restrict__ x,
                            const float* __restrict__ weight,
                            const float* __restrict__ bias,
                            float* __restrict__ out) {
    __shared__ float lds[XF];   // x tile: [row][wq][ (n*4)^(wq*4) ] swizzled

    const int t    = threadIdx.x;
    const int lane = t & 63;          // batch index n (compute phase)
    const int wv   = t >> 6;          // wave 0..3
    const int wvu  = __builtin_amdgcn_readfirstlane(wv);

    // contiguous balanced tile range for this persistent block (10 or 11)
    int tile       = (int)(((long long)blockIdx.x * NT) / NBLK);
    const int tend = (int)(((long long)(blockIdx.x + 1) * NT) / NBLK);

    // staging mapping: thread t = (n = t>>2, wq = t&3); swizzled LDS slot
    const int sn   = t >> 2;
    const int swq  = t & 3;
    const int sswz = swq * 256 + ((sn * 4) ^ (swq * 4));

    // weight pack mapping: p = q*16 + rr, q = k*9+tp (0..71), rr = tap row
    const int qb = lane >> 4;     // 0..3
    const int rr = lane & 15;

    float4 rx[12];                // staged x rows (regs, static idx)
    float  wpk[18];               // current tile's packed weights
    float  wnx[18];               // next tile's packed weights

    // ---- issue global loads for tile tl into rx / wnx (no waits) ----
    auto issue = [&](int tl) {
        const int tx = tl / NTY;
        const int ty = tl - tx * NTY;
        const int h0 = ty * H_T;
        const int w0 = tx * W_T;
        const float* gx = x + (size_t)sn * (H_IN * W_IN)
                            + (size_t)h0 * W_IN + w0 + swq * 4;
        #pragma unroll
        for (int row = 0; row < TROWS; ++row)
            rx[row] = *reinterpret_cast<const float4*>(gx + row * W_IN);
        if (rr < 9) {   // lanes rr>=9 hold padding, never readlane'd
            const float* wb = weight + ((size_t)(h0 + wv) * W_OUT + w0) * 81;
            #pragma unroll
            for (int d = 0; d < 18; ++d) {
                const int q  = 4 * d + qb;        // 0..71
                const int k  = q / 9;             // magic-mul
                const int tp = q - 9 * k;
                wnx[d] = __builtin_nontemporal_load(wb + k * 81 + rr * 9 + tp);
            }
        }
    };

    // ---- prologue: stage first tile ----
    issue(tile);
    #pragma unroll
    for (int row = 0; row < TROWS; ++row)   // compiler inserts vmcnt waits
        *reinterpret_cast<float4*>(&lds[row * 1024 + sswz]) = rx[row];
    #pragma unroll
    for (int d = 0; d < 18; ++d) wpk[d] = wnx[d];
    __syncthreads();

    while (tile < tend) {
        // issue NEXT tile's loads first: latency hides under compute below
        const int nx = (tile + 1 < tend) ? tile + 1 : tile;
        issue(nx);

        // ---- compute current tile from LDS + wpk ----
        const int tx = tile / NTY;
        const int ty = tile - tx * NTY;
        const int h0 = ty * H_T;
        const int w0 = tx * W_T;
        const int h  = h0 + wvu;

        float acc[W_T];
        {
            const float* bptr = bias + (size_t)h * W_OUT + w0;  // uniform s_load
            #pragma unroll
            for (int k = 0; k < W_T; ++k) acc[k] = bptr[k];
        }

        const float* xp0 = &lds[0 * 256 + ((lane * 4) ^ 0)  + wvu * 1024];
        const float* xp1 = &lds[1 * 256 + ((lane * 4) ^ 4)  + wvu * 1024];
        const float* xp2 = &lds[2 * 256 + ((lane * 4) ^ 8)  + wvu * 1024];
        const float* xp3 = &lds[3 * 256 + ((lane * 4) ^ 12) + wvu * 1024];

        #pragma unroll 1
        for (int r = 0; r < 9; ++r) {
            float xr[16];
            {
                const float4 v0 = *reinterpret_cast<const float4*>(xp0);
                const float4 v1 = *reinterpret_cast<const float4*>(xp1);
                const float4 v2 = *reinterpret_cast<const float4*>(xp2);
                const float4 v3 = *reinterpret_cast<const float4*>(xp3);
                xr[0]  = v0.x; xr[1]  = v0.y; xr[2]  = v0.z; xr[3]  = v0.w;
                xr[4]  = v1.x; xr[5]  = v1.y; xr[6]  = v1.z; xr[7]  = v1.w;
                xr[8]  = v2.x; xr[9]  = v2.y; xr[10] = v2.z; xr[11] = v2.w;
                xr[12] = v3.x; xr[13] = v3.y; xr[14] = v3.z; xr[15] = v3.w;
            }

            const int li0 = r;
            const int li1 = r + 16;
            const int li2 = r + 32;
            const int li3 = r + 48;

            #pragma unroll
            for (int tp = 0; tp < 9; ++tp) {
                #pragma unroll
                for (int k = 0; k < W_T; ++k) {
                    const int q  = k * 9 + tp;          // compile-time
                    const int qm = q & 3;
                    const int li = (qm == 0) ? li0 : (qm == 1) ? li1
                                 : (qm == 2) ? li2 : li3;
                    const float w = readlane_f(wpk[q >> 2], li);
                    acc[k] = fmaf(w, xr[k + tp], acc[k]);
                }
            }

            xp0 += 1024; xp1 += 1024; xp2 += 1024; xp3 += 1024;
        }

        // ---- epilogue: ReLU + nontemporal store (write-once data) ----
        {
            float* o = out + (size_t)lane * (H_OUT * W_OUT)
                           + (size_t)h * W_OUT + w0;
            f4v s;
            s.x = fmaxf(acc[0], 0.f); s.y = fmaxf(acc[1], 0.f);
            s.z = fmaxf(acc[2], 0.f); s.w = fmaxf(acc[3], 0.f);
            __builtin_nontemporal_store(s, reinterpret_cast<f4v*>(o));
            s.x = fmaxf(acc[4], 0.f); s.y = fmaxf(acc[5], 0.f);
            s.z = fmaxf(acc[6], 0.f); s.w = fmaxf(acc[7], 0.f);
            __builtin_nontemporal_store(s, reinterpret_cast<f4v*>(o + 4));
        }

        // ---- land the prefetched tile: barrier drains vmcnt (rx ready)
        // and ensures all waves finished reading LDS ----
        __syncthreads();
        #pragma unroll
        for (int row = 0; row < TROWS; ++row)
            *reinterpret_cast<float4*>(&lds[row * 1024 + sswz]) = rx[row];
        #pragma unroll
        for (int d = 0; d < 18; ++d) wpk[d] = wnx[d];
        __syncthreads();   // LDS visible; also frees rx (lgkm drained) for next issue

        ++tile;
    }
}

extern "C" void kernel_launch(void* const* d_in, const int* in_sizes, int n_in,
                              void* d_out, int out_size, void* d_ws, size_t ws_size,
                              hipStream_t stream) {
    const float* x      = (const float*)d_in[0];
    const float* weight = (const float*)d_in[1];
    const float* bias   = (const float*)d_in[2];
    float* out          = (float*)d_out;

    dim3 grid(NBLK);
    dim3 block(256);
    lc2d_kernel<<<grid, block, 0, stream>>>(x, weight, bias, out);
}

// Round 5
// 393.404 us; speedup vs baseline: 1.2215x; 1.2215x over previous
//
#include <hip/hip_runtime.h>

// LocallyConnected2D: y[n,h,w] = relu(sum_{i,j} x[n,h+i,w+j]*W[h,w,i,j] + b[h,w])
// lane = batch n (N=64=wave). History:
//  R1: scalar (SMEM) weights -> lgkmcnt drains mixed with ds_read.
//  R2: f[12] local array -> scratch (223MB writes).
//  R3: VMEM uniform weights + full unroll -> hoist pressure -> spill.
//  R4: weights via LDS broadcast (full unroll) -> hoisted ds_reads, spill.
//  R5: manual cur/nxt prefetch + memory clobber -> arrays in scratch (1.78GB).
//  R6: sched_barrier(0x7) regions -> allocator catastrophe (3.68GB scratch).
//  R7: runtime r loop, weights as per-iter uniform VMEM loads. 284us.
//  R8: weights bulk-staged to LDS, 18 broadcast ds_read_b128/iter. 205us.
//  R9: weights global->VGPR pack, hot loop readlane+fma, XOR-swizzled x LDS.
//      172us. VALUBusy 55, HBM 24% -> staging-serialization bound.
//  R10/R11: persistent + register-array prefetch (rx[12]+wnx[18] live across
//      runtime loop) -> SPILLED (FETCH 740MB, WRITE 513MB, 357us). Lesson:
//      register-array prefetch across the r-loop ALWAYS spills.
//  R12 (this): prefetch lives in LDS, not VGPRs -> global_load_lds DMA
//      (zero register footprint, queued on vmcnt).
//      - persistent blocks (512 = 2/CU), 16-slot x row-ring (64KB),
//        slot = row&15; ty-run tiles share 8/12 rows -> steady state DMAs
//        only 4 new rows (16KB)/tile, issued at top of compute, landed by
//        end-of-tile vmcnt(0)+barrier (loads span whole compute phase).
//      - weights DMA'd one tile ahead into 10.1KB LDS buffer; reg-packed via
//        18 ds_read_b32 at tile start (no VGPR arrays live across compute).
//      - DMA writes linearly (lane i -> base+16i): source pre-swizzled
//        (lane i fetches batch i^wq) so ring matches the conflict-free
//        XOR-swizzle read layout (both-sides-or-neither).
//      - hot loop identical to R9; LDS total 74.2KB -> 2 blocks/CU.

#define H_IN 512
#define W_IN 512
#define H_OUT 504
#define W_OUT 504
#define W_T 8
#define H_T 4
#define NTX 63
#define NTY 126
#define NT (NTX * NTY)        // 7938 tiles
#define NBLK 512              // 256 CUs x 2 resident blocks
#define RSLOT 16
#define RINGF (RSLOT * 1024)  // 16384 floats = 64 KB x ring
#define RMASK (RINGF - 1)
#define WOFF RINGF            // w_lds start (float index)
#define WPW 648               // 81*8 weight floats per wave
#define LDSF (RINGF + 4 * WPW) // 18976 floats = 75904 B -> 2 blocks/CU

typedef float f4v __attribute__((ext_vector_type(4)));   // nt stores

__device__ __forceinline__ float readlane_f(float v, int l) {
    return __int_as_float(__builtin_amdgcn_readlane(__float_as_int(v), l));
}

// global->LDS DMA, 16B/lane; LDS dest = wave-uniform base + lane*16
__device__ __forceinline__ void dma16(const float* g, float* l) {
    __builtin_amdgcn_global_load_lds(
        (const __attribute__((address_space(1))) unsigned int*)g,
        (__attribute__((address_space(3))) unsigned int*)l, 16, 0, 0);
}

__launch_bounds__(256, 2)
__global__ void lc2d_kernel(const float* __restrict__ x,
                            const float* __restrict__ weight,
                            const float* __restrict__ bias,
                            float* __restrict__ out) {
    __shared__ float lds[LDSF];

    const int t    = threadIdx.x;
    const int lane = t & 63;          // batch index n (compute phase)
    const int wv   = t >> 6;          // wave 0..3
    const int wvu  = __builtin_amdgcn_readfirstlane(wv);

    // contiguous balanced tile range for this persistent block (~15.5 tiles)
    int tile       = (int)(((long long)blockIdx.x * NT) / NBLK);
    const int tend = (int)(((long long)(blockIdx.x + 1) * NT) / NBLK);

    // weight pack: p = q*16 + rr, q = k*9+tp (0..71), rr = tap row.
    // reg d = p>>6 used at compile-time; lane = 16*(q&3)+rr.
    // woff[d] = per-lane LDS float offset into this wave's 648-float slice
    // (loop-invariant; statically indexed -> stays in VGPRs).
    const int qb  = lane >> 4;        // 0..3
    const int rr  = lane & 15;
    const int rrc = (rr < 9) ? rr : 8;   // clamp: padding lanes stay in-bounds
    int woff[18];
    #pragma unroll
    for (int d = 0; d < 18; ++d) {
        const int q  = 4 * d + qb;
        const int k  = q / 9;
        const int tp = q - 9 * k;
        woff[d] = k * 81 + rrc * 9 + tp;
    }

    // ---- DMA stagers (no VGPR round-trip) ----
    // ring row layout [slot][wq][i][4], i = lane; lane i carries batch i^wq
    // so reads at ((n*4)^(wq*4)) are the proven conflict-free pattern.
    auto stage_row = [&](int hi, int w0s) {
        #pragma unroll
        for (int wq = 0; wq < 4; ++wq) {
            const float* g = x + (size_t)(lane ^ wq) * (H_IN * W_IN)
                               + (size_t)hi * W_IN + w0s + wq * 4;
            dma16(g, &lds[((hi & (RSLOT - 1)) * 1024) + wq * 256]);
        }
    };
    auto stage_tile12 = [&](int h0s, int w0s) {  // wave wv: rows wv, wv+4, wv+8
        stage_row(h0s + wv,     w0s);
        stage_row(h0s + wv + 4, w0s);
        stage_row(h0s + wv + 8, w0s);
    };
    auto stage_w = [&](int h0s, int w0s) {       // 648 floats/wave, 3 DMA
        const float* wb = weight + ((size_t)(h0s + wv) * W_OUT + w0s) * 81;
        float* wl = &lds[WOFF + wv * WPW];
        dma16(wb + lane * 4,       wl);
        dma16(wb + lane * 4 + 256, wl + 256);
        if (lane < 34) dma16(wb + lane * 4 + 512, wl + 512);  // tail 136 floats
    };

    // ---- prologue: full stage of first tile (x 12 rows + weights) ----
    {
        const int tx = tile / NTY, ty = tile - tx * NTY;
        stage_tile12(ty * H_T, tx * W_T);
        stage_w(ty * H_T, tx * W_T);
    }
    asm volatile("s_waitcnt vmcnt(0)" ::: "memory");
    __syncthreads();

    while (tile < tend) {
        const int tx = tile / NTY;
        const int ty = tile - tx * NTY;
        const int h0 = ty * H_T;
        const int w0 = tx * W_T;
        const int h  = h0 + wvu;

        const bool hasnext = (tile + 1 < tend);
        const bool inrun   = hasnext && (ty + 1 < NTY);   // next tile same run
        int h0n = 0, w0n = 0;
        if (hasnext) {
            if (inrun) { h0n = h0 + H_T; w0n = w0; }
            else {
                const int txn = (tile + 1) / NTY;
                const int tyn = (tile + 1) - txn * NTY;
                h0n = tyn * H_T; w0n = txn * W_T;
            }
        }

        // (a) wpk <- w_lds (DMA'd during previous tile; landed at last barrier)
        float wpk[18];
        {
            const float* wlr = &lds[WOFF + wv * WPW];
            #pragma unroll
            for (int d = 0; d < 18; ++d) wpk[d] = wlr[woff[d]];
        }
        asm volatile("s_waitcnt lgkmcnt(0)" ::: "memory");  // reads done before
        __builtin_amdgcn_sched_barrier(0);                  // w-DMA overwrite

        // (c) prefetch NEXT tile under this tile's compute (vmcnt-queued)
        if (hasnext) {
            stage_w(h0n, w0n);                    // own wave's slice only
            if (inrun) stage_row(h0 + 12 + wv, w0);  // 4 new rows; slots are
                                                     // disjoint from current 12
        }

        float acc[W_T];
        {
            const float* bptr = bias + (size_t)h * W_OUT + w0;  // uniform s_load
            #pragma unroll
            for (int k = 0; k < W_T; ++k) acc[k] = bptr[k];
        }

        // ring read offsets (XOR-swizzled), masked per use; advance 1024/row
        int xo0 = (h0 + wvu) * 1024 + 0 * 256 + ((lane * 4) ^ 0);
        int xo1 = (h0 + wvu) * 1024 + 1 * 256 + ((lane * 4) ^ 4);
        int xo2 = (h0 + wvu) * 1024 + 2 * 256 + ((lane * 4) ^ 8);
        int xo3 = (h0 + wvu) * 1024 + 3 * 256 + ((lane * 4) ^ 12);

        #pragma unroll 1
        for (int r = 0; r < 9; ++r) {
            float xr[16];
            {
                const float4 v0 = *reinterpret_cast<const float4*>(&lds[xo0 & RMASK]);
                const float4 v1 = *reinterpret_cast<const float4*>(&lds[xo1 & RMASK]);
                const float4 v2 = *reinterpret_cast<const float4*>(&lds[xo2 & RMASK]);
                const float4 v3 = *reinterpret_cast<const float4*>(&lds[xo3 & RMASK]);
                xr[0]  = v0.x; xr[1]  = v0.y; xr[2]  = v0.z; xr[3]  = v0.w;
                xr[4]  = v1.x; xr[5]  = v1.y; xr[6]  = v1.z; xr[7]  = v1.w;
                xr[8]  = v2.x; xr[9]  = v2.y; xr[10] = v2.z; xr[11] = v2.w;
                xr[12] = v3.x; xr[13] = v3.y; xr[14] = v3.z; xr[15] = v3.w;
            }

            const int li0 = r;
            const int li1 = r + 16;
            const int li2 = r + 32;
            const int li3 = r + 48;

            #pragma unroll
            for (int tp = 0; tp < 9; ++tp) {
                #pragma unroll
                for (int k = 0; k < W_T; ++k) {
                    const int q  = k * 9 + tp;          // compile-time
                    const int qm = q & 3;
                    const int li = (qm == 0) ? li0 : (qm == 1) ? li1
                                 : (qm == 2) ? li2 : li3;
                    const float w = readlane_f(wpk[q >> 2], li);
                    acc[k] = fmaf(w, xr[k + tp], acc[k]);
                }
            }

            xo0 += 1024; xo1 += 1024; xo2 += 1024; xo3 += 1024;
        }

        // ---- epilogue: ReLU + nontemporal store (write-once data) ----
        {
            float* o = out + (size_t)lane * (H_OUT * W_OUT)
                           + (size_t)h * W_OUT + w0;
            f4v s;
            s.x = fmaxf(acc[0], 0.f); s.y = fmaxf(acc[1], 0.f);
            s.z = fmaxf(acc[2], 0.f); s.w = fmaxf(acc[3], 0.f);
            __builtin_nontemporal_store(s, reinterpret_cast<f4v*>(o));
            s.x = fmaxf(acc[4], 0.f); s.y = fmaxf(acc[5], 0.f);
            s.z = fmaxf(acc[6], 0.f); s.w = fmaxf(acc[7], 0.f);
            __builtin_nontemporal_store(s, reinterpret_cast<f4v*>(o + 4));
        }

        // land prefetch DMAs + release ring/w_lds for next iteration
        asm volatile("s_waitcnt vmcnt(0)" ::: "memory");
        __syncthreads();

        if (hasnext && !inrun) {
            // new run: full restage (targets slots current compute was using,
            // so only after the barrier above). Rare (~1 per block).
            stage_tile12(h0n, w0n);
            asm volatile("s_waitcnt vmcnt(0)" ::: "memory");
            __syncthreads();
        }
        ++tile;
    }
}

extern "C" void kernel_launch(void* const* d_in, const int* in_sizes, int n_in,
                              void* d_out, int out_size, void* d_ws, size_t ws_size,
                              hipStream_t stream) {
    const float* x      = (const float*)d_in[0];
    const float* weight = (const float*)d_in[1];
    const float* bias   = (const float*)d_in[2];
    float* out          = (float*)d_out;

    dim3 grid(NBLK);
    dim3 block(256);
    lc2d_kernel<<<grid, block, 0, stream>>>(x, weight, bias, out);
}

// Round 6
// 305.425 us; speedup vs baseline: 1.5734x; 1.2881x over previous
//
#include <hip/hip_runtime.h>

// LocallyConnected2D: y[n,h,w] = relu(sum_{i,j} x[n,h+i,w+j]*W[h,w,i,j] + b[h,w])
// lane = batch n (N=64=wave). History:
//  R1: scalar (SMEM) weights -> lgkmcnt drains mixed with ds_read.
//  R2: f[12] local array -> scratch (223MB writes).
//  R3: VMEM uniform weights + full unroll -> hoist pressure -> spill.
//  R4: weights via LDS broadcast (full unroll) -> hoisted ds_reads, spill.
//  R5: manual cur/nxt prefetch + memory clobber -> arrays in scratch (1.78GB).
//  R6: sched_barrier(0x7) regions -> allocator catastrophe (3.68GB scratch).
//  R7: runtime r loop, weights as per-iter uniform VMEM loads. 284us.
//  R8: weights bulk-staged to LDS, 18 broadcast ds_read_b128/iter. 205us.
//  R9: weights global->VGPR pack, hot loop readlane+fma, XOR-swizzled x LDS,
//      H_T=4, 3 blocks/CU. 172us @ 2.0 TB/s realized -> HBM-bound at the
//      realized BW of the scattered 64B-chunk pattern.
//  R10/R11: persistent + register-array prefetch -> SPILLED (357us). Lesson:
//      register-array prefetch across the runtime r-loop ALWAYS spills.
//  R12: global_load_lds DMA row-ring, persistent 2/CU. 274us: FETCH fell to
//      171MB but realized BW ~1TB/s -- memory system mostly idle (tiny
//      in-flight window, vmcnt(0)+barrier per tile, scattered-gather DMA
//      issue). nt stores amplified WRITE 63->110MB (no L2 write-combine).
//      Lesson: the dumb wide staging burst beats DMA pipelining here.
//  R13 (this): R9 mechanics, taller tile. H_T=8, 512-thread blocks (8 waves,
//      one output row each), TROWS=16, LDS 64KB -> 2 blocks/CU = 16 waves/CU
//      (vs R9's 12): x requested 3x->2x unique (192->128MB) AND more MLP.
//      Bijective XCD swizzle: ty-adjacent tiles (share 8/16 x rows) land on
//      the same XCD concurrently -> L2 reuse. Stores regular (R9 proof);
//      weights nt-read (read-once; keep L2 for x). Hot loop unchanged.

#define H_IN 512
#define W_IN 512
#define H_OUT 504
#define W_OUT 504
#define W_T 8
#define H_T 8
#define TROWS (H_T + 8)       // 16 staged input rows
#define XF (TROWS * 1024)     // 16384 floats = 64 KB -> 2 blocks/CU
#define NTX 63                // tiles in w
#define NTY 63                // tiles in h (504/8)
#define NBLK (NTX * NTY)      // 3969

__device__ __forceinline__ float readlane_f(float v, int l) {
    return __int_as_float(__builtin_amdgcn_readlane(__float_as_int(v), l));
}

__launch_bounds__(512, 4)
__global__ void lc2d_kernel(const float* __restrict__ x,
                            const float* __restrict__ weight,
                            const float* __restrict__ bias,
                            float* __restrict__ out) {
    __shared__ float lds[XF];   // x tile: [row][wq][ (n*4)^(wq*4) ] swizzled

    const int t    = threadIdx.x;
    const int lane = t & 63;          // batch index n (compute phase)
    const int wv   = t >> 6;          // wave 0..7

    // bijective XCD swizzle (nwg=3969, nwg%8==1): consecutive swz (= ty-
    // adjacent tiles sharing 8 x-rows) map to the same XCD, concurrently.
    int swz;
    {
        const int bid = blockIdx.x;
        const int xcd = bid & 7, i = bid >> 3;
        const int q = NBLK >> 3, r = NBLK & 7;          // 496, 1
        swz = (xcd < r ? xcd * (q + 1)
                       : r * (q + 1) + (xcd - r) * q) + i;
    }
    const int ty = swz % NTY;
    const int tx = swz / NTY;
    const int h0 = ty * H_T;
    const int w0 = tx * W_T;

    // ---- stage x tile; thread t = (n = t>>3, c = t&7 -> wq = c&3, rp = c>>2)
    // 8 reps x 2 rows: rows rp, rp+2, ..., rp+14. Coalesced 64B per 4 threads.
    // LDS float addr = row*1024 + wq*256 + (n*4 ^ wq*4): conflict-min writes,
    // and reads below use the proven conflict-free XOR pattern.
    {
        const int n  = t >> 3;
        const int c  = t & 7;
        const int wq = c & 3;
        const int rp = c >> 2;
        const float* gx = x + (size_t)n * (H_IN * W_IN)
                            + (size_t)(h0 + rp) * W_IN + w0 + wq * 4;
        float* ld = &lds[rp * 1024 + wq * 256 + ((n * 4) ^ (wq * 4))];
        #pragma unroll
        for (int rep = 0; rep < 8; ++rep) {
            const float4 v = *reinterpret_cast<const float4*>(gx + rep * 2 * W_IN);
            *reinterpret_cast<float4*>(ld + rep * 2048) = v;
        }
    }

    // ---- weights: per-wave gather global -> 18 VGPRs, packed p = q*16 + rr
    // (q = k*9+tp in 0..71, rr = tap row, slots rr=9..15 padding).
    // nt loads: read-once stream, don't evict x from L2.
    float wpk[18];
    {
        const float* wb = weight + ((size_t)(h0 + wv) * W_OUT + w0) * 81;
        const int qb = lane >> 4;     // 0..3
        const int rr = lane & 15;
        #pragma unroll
        for (int d = 0; d < 18; ++d) {
            const int q  = 4 * d + qb;        // 0..71
            const int k  = q / 9;             // magic-mul
            const int tp = q - 9 * k;
            float v = 0.f;
            if (rr < 9) v = __builtin_nontemporal_load(wb + k * 81 + rr * 9 + tp);
            wpk[d] = v;
        }
    }

    __syncthreads();

    const int wvu = __builtin_amdgcn_readfirstlane(wv);
    const int h   = h0 + wvu;                      // this wave's output row

    float acc[W_T];
    {
        const float* bptr = bias + (size_t)h * W_OUT + w0;   // uniform: s_load
        #pragma unroll
        for (int k = 0; k < W_T; ++k) acc[k] = bptr[k];
    }

    // 4 swizzled x chunk pointers for this lane; row offset advances 1024/iter
    const float* xp0 = &lds[0 * 256 + ((lane * 4) ^ 0)  + wvu * 1024];
    const float* xp1 = &lds[1 * 256 + ((lane * 4) ^ 4)  + wvu * 1024];
    const float* xp2 = &lds[2 * 256 + ((lane * 4) ^ 8)  + wvu * 1024];
    const float* xp3 = &lds[3 * 256 + ((lane * 4) ^ 12) + wvu * 1024];

    #pragma unroll 1
    for (int r = 0; r < 9; ++r) {
        // x row (wvu + r): 16 floats/lane via 4 conflict-free ds_read_b128
        float xr[16];
        {
            const float4 v0 = *reinterpret_cast<const float4*>(xp0);
            const float4 v1 = *reinterpret_cast<const float4*>(xp1);
            const float4 v2 = *reinterpret_cast<const float4*>(xp2);
            const float4 v3 = *reinterpret_cast<const float4*>(xp3);
            xr[0]  = v0.x; xr[1]  = v0.y; xr[2]  = v0.z; xr[3]  = v0.w;
            xr[4]  = v1.x; xr[5]  = v1.y; xr[6]  = v1.z; xr[7]  = v1.w;
            xr[8]  = v2.x; xr[9]  = v2.y; xr[10] = v2.z; xr[11] = v2.w;
            xr[12] = v3.x; xr[13] = v3.y; xr[14] = v3.z; xr[15] = v3.w;
        }

        const int li0 = r;
        const int li1 = r + 16;
        const int li2 = r + 32;
        const int li3 = r + 48;

        #pragma unroll
        for (int tp = 0; tp < 9; ++tp) {
            #pragma unroll
            for (int k = 0; k < W_T; ++k) {
                const int q  = k * 9 + tp;          // compile-time
                const int qm = q & 3;
                const int li = (qm == 0) ? li0 : (qm == 1) ? li1
                             : (qm == 2) ? li2 : li3;
                const float w = readlane_f(wpk[q >> 2], li);
                acc[k] = fmaf(w, xr[k + tp], acc[k]);
            }
        }

        xp0 += 1024; xp1 += 1024; xp2 += 1024; xp3 += 1024;
    }

    // ---- epilogue: ReLU + regular stores (L2 write-combining; R9 proved
    // WRITE == output size with plain stores, nt amplified it 1.7x) ----
    float* o = out + (size_t)lane * (H_OUT * W_OUT) + (size_t)h * W_OUT + w0;
    float4 s;
    s.x = fmaxf(acc[0], 0.f); s.y = fmaxf(acc[1], 0.f);
    s.z = fmaxf(acc[2], 0.f); s.w = fmaxf(acc[3], 0.f);
    *reinterpret_cast<float4*>(o) = s;
    s.x = fmaxf(acc[4], 0.f); s.y = fmaxf(acc[5], 0.f);
    s.z = fmaxf(acc[6], 0.f); s.w = fmaxf(acc[7], 0.f);
    *reinterpret_cast<float4*>(o + 4) = s;
}

extern "C" void kernel_launch(void* const* d_in, const int* in_sizes, int n_in,
                              void* d_out, int out_size, void* d_ws, size_t ws_size,
                              hipStream_t stream) {
    const float* x      = (const float*)d_in[0];
    const float* weight = (const float*)d_in[1];
    const float* bias   = (const float*)d_in[2];
    float* out          = (float*)d_out;

    dim3 grid(NBLK);
    dim3 block(512);
    lc2d_kernel<<<grid, block, 0, stream>>>(x, weight, bias, out);
}